// Round 3
// baseline (82.620 us; speedup 1.0000x reference)
//
#include <hip/hip_runtime.h>
#include <math.h>

#define BB 64          // batch
#define CC 16          // children per sample
#define DD 512         // feature dim
#define LL 8192        // CC*DD flattened length
#define EPSV 1e-8f
#define INVT 10.0f     // 1/TEMPERATURE
#define NEGINF_T (-1e31f)

// ws layout (floats):
//  [0,     1024)  n2i : ||ci row r||^2   (r = b*16+c)
//  [1024,  2048)  n2j : ||cj row r||^2
//  [2048,  6144)  dj  : raw gathered dots vs cj  [64,64]
//  [6144, 10240)  dk  : raw gathered dots vs ci  [64,64]
//  [10240,10304)  pos : dot(fi, fj) per anchor
#define WS_N2I 0
#define WS_N2J 1024
#define WS_DJ  2048
#define WS_DK  6144
#define WS_POS 10240

__device__ __forceinline__ float dot4(float4 a, float4 b) {
    return a.x * b.x + a.y * b.y + a.z * b.z + a.w * b.w;
}

__device__ __forceinline__ float wave_reduce(float v) {
    #pragma unroll
    for (int off = 32; off; off >>= 1) v += __shfl_down(v, off);
    return v;
}

// ---------------------------------------------------------------------------
// sim (fused with prep): block (j, ig). Stages cj[j] + ci[j] (64 KB) in LDS;
// every gather then hits LDS (wave-uniform child row, stride-1 b128 reads).
// Each wave computes complete (i,j) dots for its 2 anchors -> no in-loop
// barriers. ig==0 blocks also emit the child-row norms of sample j; the
// diagonal wave (i==j) also emits the positive-pair dot.
// ---------------------------------------------------------------------------
__global__ __launch_bounds__(256) void ntx_sim(const float* __restrict__ ci,
                                               const float* __restrict__ cj,
                                               const int* __restrict__ nj,
                                               const int* __restrict__ nk,
                                               float* __restrict__ ws,
                                               float* __restrict__ out) {
    const int j   = blockIdx.x;   // 0..63 : negative-source sample
    const int ig  = blockIdx.y;   // 0..7  : anchor group
    const int tid = threadIdx.x;

    __shared__ float scj[LL];        // cj[j] rows
    __shared__ float sci[LL];        // ci[j] rows
    __shared__ int   sidx[2][8][CC]; // [side][t][c], i = ig + 8*t

    float4* s4j = (float4*)scj;
    float4* s4i = (float4*)sci;
    const float4* gcj = (const float4*)(cj + j * LL);
    const float4* gci = (const float4*)(ci + j * LL);
    #pragma unroll
    for (int t = 0; t < 8; ++t) {
        s4j[tid + 256 * t] = gcj[tid + 256 * t];
        s4i[tid + 256 * t] = gci[tid + 256 * t];
    }
    {   // 256 ints: one per thread, coalesced in 64B runs
        const int t = tid >> 5, side = (tid >> 4) & 1, c = tid & 15;
        const int i = ig + 8 * t;
        const int* src = side ? nk : nj;
        sidx[side][t][c] = src[(i * BB + j) * CC + c];
    }
    if (j == 0 && ig == 0 && tid == 0) out[0] = 0.f;  // final accumulates atomically
    __syncthreads();

    const int wave = tid >> 6, lane = tid & 63;

    // per-child squared norms of sample j (once per j, from staged LDS)
    if (ig == 0) {
        #pragma unroll
        for (int r8 = 0; r8 < 8; ++r8) {
            const int r  = wave * 8 + r8;        // 0..31
            const int rr = r & 15;
            const float4* src = (r < 16) ? s4j : s4i;
            float4 a = src[rr * 128 + lane];
            float4 b = src[rr * 128 + 64 + lane];
            float acc = dot4(a, a) + dot4(b, b);
            acc = wave_reduce(acc);
            if (lane == 0) ws[(r < 16 ? WS_N2J : WS_N2I) + j * CC + rr] = acc;
        }
    }

    // main: wave handles anchors i = ig + 8*(2*wave + tt)
    #pragma unroll
    for (int tt = 0; tt < 2; ++tt) {
        const int t = 2 * wave + tt;
        const int i = ig + 8 * t;
        const float4* fi4 = (const float4*)(ci + i * LL);
        const bool diag = (i == j);              // wave-uniform
        float aj = 0.f, ak = 0.f, ap = 0.f;
        #pragma unroll
        for (int c = 0; c < CC; ++c) {
            const int rj = sidx[0][t][c];
            const int rk = sidx[1][t][c];
            #pragma unroll
            for (int h = 0; h < 2; ++h) {
                const int o = h * 64 + lane;
                float4 fv = fi4[c * 128 + o];
                float4 vj = s4j[rj * 128 + o];
                float4 vk = s4i[rk * 128 + o];
                aj += dot4(fv, vj);
                ak += dot4(fv, vk);
                if (diag) ap += dot4(fv, s4j[c * 128 + o]);
            }
        }
        aj = wave_reduce(aj);
        ak = wave_reduce(ak);
        if (lane == 0) {
            ws[WS_DJ + i * BB + j] = aj;
            ws[WS_DK + i * BB + j] = ak;
        }
        if (diag) {
            ap = wave_reduce(ap);
            if (lane == 0) ws[WS_POS + i] = ap;
        }
    }
}

// ---------------------------------------------------------------------------
// final: block i, lane j. Normalize raw dots, masked logsumexp over 129
// logits via wave butterfly, atomicAdd loss_i/(2B) into out.
// ---------------------------------------------------------------------------
__global__ __launch_bounds__(64) void ntx_final(const int* __restrict__ pids,
                                                const int* __restrict__ nj,
                                                const int* __restrict__ nk,
                                                const float* __restrict__ ws,
                                                float* __restrict__ out) {
    const int i = blockIdx.x, j = threadIdx.x;
    __shared__ float sn2i[1024], sn2j[1024];
    const float4* n2i4 = (const float4*)(ws + WS_N2I);
    const float4* n2j4 = (const float4*)(ws + WS_N2J);
    #pragma unroll
    for (int t = 0; t < 4; ++t) {
        ((float4*)sn2i)[j + 64 * t] = n2i4[j + 64 * t];
        ((float4*)sn2j)[j + 64 * t] = n2j4[j + 64 * t];
    }
    __syncthreads();

    float si = 0.f, sjf = 0.f;
    #pragma unroll
    for (int c = 0; c < CC; ++c) { si += sn2i[i * CC + c]; sjf += sn2j[i * CC + c]; }
    const float ni = fmaxf(sqrtf(si), EPSV);
    const float l0 = ws[WS_POS + i] / (ni * fmaxf(sqrtf(sjf), EPSV)) * INVT;

    float gj = 0.f, gk = 0.f;
    #pragma unroll
    for (int c = 0; c < CC; ++c) {
        gj += sn2j[j * CC + nj[(i * BB + j) * CC + c]];
        gk += sn2i[j * CC + nk[(i * BB + j) * CC + c]];
    }

    const bool valid = (j != i) && (pids[j] != pids[i]);
    float lj = NEGINF_T, lk = NEGINF_T;
    if (valid) {
        const float inv = INVT / ni;
        lj = ws[WS_DJ + i * BB + j] / fmaxf(sqrtf(gj), EPSV) * inv;
        lk = ws[WS_DK + i * BB + j] / fmaxf(sqrtf(gk), EPSV) * inv;
    }

    float m = fmaxf(lj, lk);
    #pragma unroll
    for (int off = 32; off; off >>= 1) m = fmaxf(m, __shfl_xor(m, off));
    m = fmaxf(m, l0);

    float s = __expf(lj - m) + __expf(lk - m);
    s = wave_reduce(s);
    if (j == 0) {
        s += __expf(l0 - m);
        const float loss_i = -l0 + m + __logf(s);
        atomicAdd(out, loss_i * (1.0f / (2.0f * BB)));
    }
}

// ---------------------------------------------------------------------------
extern "C" void kernel_launch(void* const* d_in, const int* in_sizes, int n_in,
                              void* d_out, int out_size, void* d_ws, size_t ws_size,
                              hipStream_t stream) {
    const float* ci  = (const float*)d_in[0];
    const float* cj  = (const float*)d_in[1];
    const int*  pids = (const int*) d_in[2];
    const int*  nj   = (const int*) d_in[3];
    const int*  nk   = (const int*) d_in[4];
    float* ws  = (float*)d_ws;
    float* out = (float*)d_out;

    ntx_sim<<<dim3(BB, 8), 256, 0, stream>>>(ci, cj, nj, nk, ws, out);
    ntx_final<<<BB, 64, 0, stream>>>(pids, nj, nk, ws, out);
}